// Round 9
// baseline (262.586 us; speedup 1.0000x reference)
//
#include <hip/hip_runtime.h>
#include <math.h>

#define BB 2
#define LL 1536
#define DD 768
#define HH 12
#define DKK 64
#define ZNEG -5.0e8f   // NEG/2: reference masks scores to -1e9, then z = scores/2

typedef __attribute__((ext_vector_type(8))) short bf16x8;           // 8 bf16 (4 VGPRs)
typedef __attribute__((ext_vector_type(8))) unsigned short u16x8;
typedef __attribute__((ext_vector_type(4))) float f32x4;

__device__ __forceinline__ unsigned short f32_to_bf16_rn(float x) {
    unsigned int u = __float_as_uint(x);
    u += 0x7fffu + ((u >> 16) & 1u);          // round-to-nearest-even
    return (unsigned short)(u >> 16);
}
__device__ __forceinline__ float bf16u_to_f32(unsigned short h) {
    return __uint_as_float(((unsigned int)h) << 16);
}

// Split 8 consecutive f32 into bf16 hi/lo halves; store 16 B of each.
__device__ __forceinline__ void split8(const float* __restrict__ gsrc,
                                       unsigned short* __restrict__ hdst,
                                       unsigned short* __restrict__ ldst) {
    float4 v0 = *reinterpret_cast<const float4*>(gsrc);
    float4 v1 = *reinterpret_cast<const float4*>(gsrc + 4);
    float f[8] = {v0.x, v0.y, v0.z, v0.w, v1.x, v1.y, v1.z, v1.w};
    u16x8 hi, lo;
    #pragma unroll
    for (int i = 0; i < 8; ++i) {
        unsigned short h = f32_to_bf16_rn(f[i]);
        float r = f[i] - bf16u_to_f32(h);
        hi[i] = h;
        lo[i] = f32_to_bf16_rn(r);
    }
    *reinterpret_cast<u16x8*>(hdst) = hi;
    *reinterpret_cast<u16x8*>(ldst) = lo;
}

// 16B async global->LDS DMA (gfx950). Dest = wave-uniform base + lane*16;
// source is per-lane, so we pre-permute the GLOBAL address (m97/m173 pattern).
__device__ __forceinline__ void glds16(const unsigned short* g, unsigned short* s) {
    __builtin_amdgcn_global_load_lds(
        (const __attribute__((address_space(1))) unsigned short*)g,
        (__attribute__((address_space(3))) unsigned short*)s, 16, 0, 0);
}

// ---------------------------------------------------------------------------
// Kernel 0: ALL presplits in one launch (saves 3 launch overheads vs r8).
// Block ranges: [0,1152) query, [1152,2304) key, [2304,2592) wq, [2592,2880) wk.
// ---------------------------------------------------------------------------
__global__ __launch_bounds__(256) void presplit_all(
    const float* __restrict__ q,  const float* __restrict__ k,
    const float* __restrict__ wq, const float* __restrict__ wk,
    unsigned short* __restrict__ Xqh, unsigned short* __restrict__ Xql,
    unsigned short* __restrict__ Xkh, unsigned short* __restrict__ Xkl,
    unsigned short* __restrict__ Wqh, unsigned short* __restrict__ Wql,
    unsigned short* __restrict__ Wkh, unsigned short* __restrict__ Wkl)
{
    const int blk = blockIdx.x;
    const float* src;
    unsigned short *h, *l;
    int base;
    if (blk < 1152)      { src = q;  h = Xqh; l = Xql; base = blk; }
    else if (blk < 2304) { src = k;  h = Xkh; l = Xkl; base = blk - 1152; }
    else if (blk < 2592) { src = wq; h = Wqh; l = Wql; base = blk - 2304; }
    else                 { src = wk; h = Wkh; l = Wkl; base = blk - 2592; }
    const int i = (base * 256 + (int)threadIdx.x) * 8;
    split8(src + i, h + i, l + i);
}

// ---------------------------------------------------------------------------
// Kernel 1: fused Q/K projection via split-bf16 MFMA (r8 verified, 64.7 us).
// Staging: global_load_lds(16B) from PRE-SPLIT inputs, slot-inverse swizzled
// global source + linear LDS dest. Epilogue stores pre-split hi/lo for K2.
// ---------------------------------------------------------------------------
__global__ __launch_bounds__(256) void proj_mfma(
    const unsigned short* __restrict__ Xqh, const unsigned short* __restrict__ Xql,
    const unsigned short* __restrict__ Xkh, const unsigned short* __restrict__ Xkl,
    const unsigned short* __restrict__ Wqh, const unsigned short* __restrict__ Wql,
    const unsigned short* __restrict__ Wkh, const unsigned short* __restrict__ Wkl,
    const float* __restrict__ bq, const float* __restrict__ bk,
    unsigned short* __restrict__ Qh, unsigned short* __restrict__ Ql,
    unsigned short* __restrict__ Kh, unsigned short* __restrict__ Kl)
{
    const unsigned short* Xh = blockIdx.z ? Xkh : Xqh;
    const unsigned short* Xl = blockIdx.z ? Xkl : Xql;
    const unsigned short* Wh = blockIdx.z ? Wkh : Wqh;
    const unsigned short* Wl = blockIdx.z ? Wkl : Wql;
    const float* bias = blockIdx.z ? bk : bq;
    unsigned short* Oh = blockIdx.z ? Kh : Qh;
    unsigned short* Ol = blockIdx.z ? Kl : Ql;

    __shared__ alignas(16) unsigned short Ah[8 * 64 * 8];  // 8 KB
    __shared__ alignas(16) unsigned short Al[8 * 64 * 8];  // 8 KB
    __shared__ alignas(16) unsigned short Bh[4 * 64 * 8];  // 4 KB
    __shared__ alignas(16) unsigned short Bl[4 * 64 * 8];  // 4 KB

    const int tid  = threadIdx.x;
    const int lane = tid & 63;
    const int w    = tid >> 6;
    const int wm   = w & 1;          // 2 m-halves of 64 rows
    const int wn   = w >> 1;         // 2 n-halves of 32 cols
    const int m0   = blockIdx.y * 128;
    const int n0   = blockIdx.x * 64;

    // ---- precompute per-lane staging sources (slot-inverse swizzle) ----
    int offA[2];
    #pragma unroll
    for (int j = 0; j < 2; ++j) {
        const int s = w * 128 + j * 64 + lane;
        const int m = ((s >> 6) << 4) | (s & 15);
        const int g = (s >> 4) & 3;
        offA[j] = (m0 + m) * DD + g * 8;
    }
    int offB;
    {
        const int s = w * 64 + lane;
        const int n = ((s >> 6) << 4) | (s & 15);
        const int g = (s >> 4) & 3;
        offB = (n0 + n) * DD + g * 8;
    }

    f32x4 acc[4][2] = {};

    for (int k0 = 0; k0 < DD; k0 += 32) {
        #pragma unroll
        for (int j = 0; j < 2; ++j) {
            unsigned short* dstH = Ah + (size_t)(w * 128 + j * 64) * 8;
            unsigned short* dstL = Al + (size_t)(w * 128 + j * 64) * 8;
            glds16(Xh + offA[j] + k0, dstH);
            glds16(Xl + offA[j] + k0, dstL);
        }
        glds16(Wh + offB + k0, Bh + (size_t)(w * 64) * 8);
        glds16(Wl + offB + k0, Bl + (size_t)(w * 64) * 8);
        __syncthreads();   // drains vmcnt -> DMA complete

        bf16x8 aH[4], aL[4], bH[2], bL[2];
        #pragma unroll
        for (int fm = 0; fm < 4; ++fm) {
            const int f = wm * 4 + fm;
            aH[fm] = *reinterpret_cast<const bf16x8*>(Ah + (f * 64 + lane) * 8);
            aL[fm] = *reinterpret_cast<const bf16x8*>(Al + (f * 64 + lane) * 8);
        }
        #pragma unroll
        for (int fn = 0; fn < 2; ++fn) {
            const int f = wn * 2 + fn;
            bH[fn] = *reinterpret_cast<const bf16x8*>(Bh + (f * 64 + lane) * 8);
            bL[fn] = *reinterpret_cast<const bf16x8*>(Bl + (f * 64 + lane) * 8);
        }
        #pragma unroll
        for (int fm = 0; fm < 4; ++fm)
            #pragma unroll
            for (int fn = 0; fn < 2; ++fn) {
                acc[fm][fn] = __builtin_amdgcn_mfma_f32_16x16x32_bf16(aH[fm], bH[fn], acc[fm][fn], 0, 0, 0);
                acc[fm][fn] = __builtin_amdgcn_mfma_f32_16x16x32_bf16(aH[fm], bL[fn], acc[fm][fn], 0, 0, 0);
                acc[fm][fn] = __builtin_amdgcn_mfma_f32_16x16x32_bf16(aL[fm], bH[fn], acc[fm][fn], 0, 0, 0);
            }
        __syncthreads();
    }

    // ---- epilogue: C/D layout col=lane&15, row=(lane>>4)*4+reg [m89] ----
    const int r0 = (lane >> 4) << 2;
    const int cl = lane & 15;
    #pragma unroll
    for (int fn = 0; fn < 2; ++fn) {
        const int col = n0 + wn * 32 + fn * 16 + cl;
        const float bv = bias[col];
        #pragma unroll
        for (int fm = 0; fm < 4; ++fm) {
            const int row = m0 + wm * 64 + fm * 16 + r0;
            #pragma unroll
            for (int r = 0; r < 4; ++r) {
                const float v = acc[fm][fn][r] + bv;
                const unsigned short h16 = f32_to_bf16_rn(v);
                const float res = v - bf16u_to_f32(h16);
                const size_t o = (size_t)(row + r) * DD + col;
                Oh[o] = h16;
                Ol[o] = f32_to_bf16_rn(res);
            }
        }
    }
}

// ---------------------------------------------------------------------------
// Kernel 2: scores z = (q.k)/16, masked keys -> ZNEG, split-bf16 MFMA
// (r8 structure unchanged: global_load_lds staging, slot-inverse source).
// ---------------------------------------------------------------------------
__global__ __launch_bounds__(256) void scores_mfma(
    const unsigned short* __restrict__ Qh, const unsigned short* __restrict__ Ql,
    const unsigned short* __restrict__ Kh, const unsigned short* __restrict__ Kl,
    const int* __restrict__ mask, float* __restrict__ S)
{
    const int bh = blockIdx.z;
    const int b  = bh / HH;
    const int h  = bh - b * HH;
    const int q0 = blockIdx.y * 128;
    const int n0 = blockIdx.x * 64;

    __shared__ alignas(16) unsigned short Ah[8 * 2 * 64 * 8];  // 16 KB
    __shared__ alignas(16) unsigned short Al[8 * 2 * 64 * 8];  // 16 KB
    __shared__ alignas(16) unsigned short Bh[4 * 2 * 64 * 8];  //  8 KB
    __shared__ alignas(16) unsigned short Bl[4 * 2 * 64 * 8];  //  8 KB

    const int tid  = threadIdx.x;
    const int lane = tid & 63;
    const int w    = tid >> 6;
    const int wm   = w & 1;
    const int wn   = w >> 1;

    // ---- stage A: 1024 chunks; wave w owns s in [w*256, w*256+256) ----
    #pragma unroll
    for (int j = 0; j < 4; ++j) {
        const int s = w * 256 + j * 64 + lane;
        const int m  = ((s >> 7) << 4) | (s & 15);
        const int qq = (s >> 6) & 1;
        const int g  = (s >> 4) & 3;
        const size_t o = (size_t)(b * LL + q0 + m) * DD + h * DKK + qq * 32 + g * 8;
        glds16(Qh + o, Ah + (size_t)(w * 256 + j * 64) * 8);
        glds16(Ql + o, Al + (size_t)(w * 256 + j * 64) * 8);
    }
    // ---- stage B: 512 chunks; wave w owns s in [w*128, w*128+128) ----
    #pragma unroll
    for (int j = 0; j < 2; ++j) {
        const int s = w * 128 + j * 64 + lane;
        const int n  = ((s >> 7) << 4) | (s & 15);
        const int qq = (s >> 6) & 1;
        const int g  = (s >> 4) & 3;
        const size_t o = (size_t)(b * LL + n0 + n) * DD + h * DKK + qq * 32 + g * 8;
        glds16(Kh + o, Bh + (size_t)(w * 128 + j * 64) * 8);
        glds16(Kl + o, Bl + (size_t)(w * 128 + j * 64) * 8);
    }
    __syncthreads();   // drains vmcnt -> DMA complete

    f32x4 acc[4][2] = {};
    #pragma unroll
    for (int qq = 0; qq < 2; ++qq) {
        bf16x8 aH[4], aL[4], bH[2], bL[2];
        #pragma unroll
        for (int fm = 0; fm < 4; ++fm) {
            const int f = (wm * 4 + fm) * 2 + qq;
            aH[fm] = *reinterpret_cast<const bf16x8*>(Ah + (f * 64 + lane) * 8);
            aL[fm] = *reinterpret_cast<const bf16x8*>(Al + (f * 64 + lane) * 8);
        }
        #pragma unroll
        for (int fn = 0; fn < 2; ++fn) {
            const int f = (wn * 2 + fn) * 2 + qq;
            bH[fn] = *reinterpret_cast<const bf16x8*>(Bh + (f * 64 + lane) * 8);
            bL[fn] = *reinterpret_cast<const bf16x8*>(Bl + (f * 64 + lane) * 8);
        }
        #pragma unroll
        for (int fm = 0; fm < 4; ++fm)
            #pragma unroll
            for (int fn = 0; fn < 2; ++fn) {
                acc[fm][fn] = __builtin_amdgcn_mfma_f32_16x16x32_bf16(aH[fm], bH[fn], acc[fm][fn], 0, 0, 0);
                acc[fm][fn] = __builtin_amdgcn_mfma_f32_16x16x32_bf16(aH[fm], bL[fn], acc[fm][fn], 0, 0, 0);
                acc[fm][fn] = __builtin_amdgcn_mfma_f32_16x16x32_bf16(aL[fm], bH[fn], acc[fm][fn], 0, 0, 0);
            }
    }

    // ---- epilogue: scale 1/16, mask, store f32 ----
    const int r0 = (lane >> 4) << 2;
    const int cl = lane & 15;
    #pragma unroll
    for (int fn = 0; fn < 2; ++fn) {
        const int col = n0 + wn * 32 + fn * 16 + cl;
        const int mk  = mask[b * LL + col];
        #pragma unroll
        for (int fm = 0; fm < 4; ++fm) {
            const int row = q0 + wm * 64 + fm * 16 + r0;
            const size_t base = ((size_t)bh * LL + row) * LL + col;
            #pragma unroll
            for (int r = 0; r < 4; ++r) {
                const float v = acc[fm][fn][r] * 0.0625f;   // (qk/8)/2
                S[base + (size_t)r * LL] = mk ? v : ZNEG;
            }
        }
    }
}

// ---------------------------------------------------------------------------
// Kernel 3: entmax-1.5, wave-per-head, 3-HEAD ILP INTERLEAVE.
// Same verified math as r7 (8 bisections + quadratic finish) but the wave's
// 3 heads run concurrently: three independent brackets, butterflies
// interleaved so shuffle latency hides under the other heads' VALU.
// ---------------------------------------------------------------------------
__global__ __launch_bounds__(256) void entmax_sum(
    const float* __restrict__ S, float* __restrict__ out)
{
    const int bq = blockIdx.x;          // b*LL + q
    const int b  = bq / LL;
    const int q  = bq - b * LL;
    const int tid = threadIdx.x;
    const int w  = tid >> 6;            // wave 0..3
    const int l  = tid & 63;            // lane 0..63

    __shared__ float buf[4][LL];        // per-wave head-partials, 24 KB

    float acc[24];
    #pragma unroll
    for (int i = 0; i < 24; ++i) acc[i] = 0.0f;

    // ---- load all 3 heads' chunks ----
    float z[3][24];
    #pragma unroll
    for (int hh = 0; hh < 3; ++hh) {
        const int h = w + (hh << 2);
        const float* row = S + ((size_t)(b * HH + h) * LL + q) * LL + l * 24;
        #pragma unroll
        for (int i = 0; i < 24; i += 4) {
            float4 v = *reinterpret_cast<const float4*>(row + i);
            z[hh][i] = v.x; z[hh][i + 1] = v.y; z[hh][i + 2] = v.z; z[hh][i + 3] = v.w;
        }
    }

    // ---- 3 interleaved wave-maxes + shift ----
    float m[3];
    #pragma unroll
    for (int hh = 0; hh < 3; ++hh) {
        m[hh] = z[hh][0];
        #pragma unroll
        for (int i = 1; i < 24; ++i) m[hh] = fmaxf(m[hh], z[hh][i]);
    }
    #pragma unroll
    for (int off = 32; off > 0; off >>= 1)
        #pragma unroll
        for (int hh = 0; hh < 3; ++hh)
            m[hh] = fmaxf(m[hh], __shfl_xor(m[hh], off, 64));
    #pragma unroll
    for (int hh = 0; hh < 3; ++hh)
        #pragma unroll
        for (int i = 0; i < 24; ++i) z[hh][i] -= m[hh];

    // ---- 8 interleaved bisection steps: tau in [-1, 0] ----
    float lo[3] = {-1.0f, -1.0f, -1.0f}, hi_[3] = {0.0f, 0.0f, 0.0f};
    #pragma unroll
    for (int it = 0; it < 8; ++it) {
        float tau[3], s[3] = {0.0f, 0.0f, 0.0f};
        #pragma unroll
        for (int hh = 0; hh < 3; ++hh) tau[hh] = 0.5f * (lo[hh] + hi_[hh]);
        #pragma unroll
        for (int i = 0; i < 24; ++i)
            #pragma unroll
            for (int hh = 0; hh < 3; ++hh) {
                const float t = fmaxf(z[hh][i] - tau[hh], 0.0f);
                s[hh] = fmaf(t, t, s[hh]);
            }
        #pragma unroll
        for (int off = 32; off > 0; off >>= 1)
            #pragma unroll
            for (int hh = 0; hh < 3; ++hh)
                s[hh] += __shfl_xor(s[hh], off, 64);
        #pragma unroll
        for (int hh = 0; hh < 3; ++hh) {
            if (s[hh] >= 1.0f) lo[hh] = tau[hh]; else hi_[hh] = tau[hh];
        }
    }

    // ---- 3 interleaved closed-form quadratic finishes on A = {z > lo} ----
    float s1[3] = {0,0,0}, s2[3] = {0,0,0}, cn[3] = {0,0,0};
    #pragma unroll
    for (int i = 0; i < 24; ++i)
        #pragma unroll
        for (int hh = 0; hh < 3; ++hh) {
            const bool a = z[hh][i] > lo[hh];
            const float t = a ? z[hh][i] : 0.0f;
            s1[hh] += t;
            s2[hh] = fmaf(t, t, s2[hh]);
            cn[hh] += a ? 1.0f : 0.0f;
        }
    #pragma unroll
    for (int off = 32; off > 0; off >>= 1)
        #pragma unroll
        for (int hh = 0; hh < 3; ++hh) {
            s1[hh] += __shfl_xor(s1[hh], off, 64);
            s2[hh] += __shfl_xor(s2[hh], off, 64);
            cn[hh] += __shfl_xor(cn[hh], off, 64);
        }
    float tauF[3];
    #pragma unroll
    for (int hh = 0; hh < 3; ++hh) {
        const float disc = fmaxf(fmaf(s1[hh], s1[hh], -cn[hh] * (s2[hh] - 1.0f)), 0.0f);
        tauF[hh] = (s1[hh] - sqrtf(disc)) / cn[hh];   // cn >= 1 (max elem z=0 > lo)
    }

    // ---- p accumulation over the 3 heads ----
    #pragma unroll
    for (int i = 0; i < 24; ++i)
        #pragma unroll
        for (int hh = 0; hh < 3; ++hh) {
            const float t = fmaxf(z[hh][i] - tauF[hh], 0.0f);
            acc[i] = fmaf(t, t, acc[i]);
        }

    // ---- join the 4 waves' head-partials ----
    #pragma unroll
    for (int i = 0; i < 24; ++i) buf[w][l * 24 + i] = acc[i];
    __syncthreads();

    float* orow = out + (size_t)bq * LL;
    #pragma unroll
    for (int i = 0; i < 6; ++i) {
        const int c = tid + (i << 8);
        orow[c] = (buf[0][c] + buf[1][c] + buf[2][c] + buf[3][c]) * (1.0f / 12.0f);
    }
}

// ---------------------------------------------------------------------------
extern "C" void kernel_launch(void* const* d_in, const int* in_sizes, int n_in,
                              void* d_out, int out_size, void* d_ws, size_t ws_size,
                              hipStream_t stream) {
    (void)in_sizes; (void)n_in; (void)out_size; (void)ws_size;
    const float* query = (const float*)d_in[0];
    const float* key   = (const float*)d_in[1];
    const int*   mask  = (const int*)d_in[2];
    const float* wq_w  = (const float*)d_in[3];
    const float* wq_b  = (const float*)d_in[4];
    const float* wk_w  = (const float*)d_in[5];
    const float* wk_b  = (const float*)d_in[6];
    float* out = (float*)d_out;

    const size_t NE = (size_t)BB * LL * DD;         // 2359296 elems
    const size_t NW = (size_t)DD * DD;              //  589824 elems
    unsigned short* Qh = (unsigned short*)d_ws;     // 4.7 MB each
    unsigned short* Ql = Qh + NE;
    unsigned short* Kh = Ql + NE;
    unsigned short* Kl = Kh + NE;
    float* S = (float*)(Kl + NE);                   // [B,H,L,L] 226.5 MB

    // Presplit arrays alias the S region (dead until K2 overwrites it).
    unsigned short* Xqh = (unsigned short*)S;
    unsigned short* Xql = Xqh + NE;
    unsigned short* Xkh = Xql + NE;
    unsigned short* Xkl = Xkh + NE;
    unsigned short* Wqh = Xkl + NE;
    unsigned short* Wql = Wqh + NW;
    unsigned short* Wkh = Wql + NW;
    unsigned short* Wkl = Wkh + NW;

    // K0: all presplits in ONE launch (2880 blocks)
    presplit_all<<<2880, 256, 0, stream>>>(
        query, key, wq_w, wk_w, Xqh, Xql, Xkh, Xkl, Wqh, Wql, Wkh, Wkl);

    // K1: projections -> pre-split bf16 hi/lo (z dim: 0 = Q, 1 = K)
    proj_mfma<<<dim3(DD / 64, (BB * LL) / 128, 2), 256, 0, stream>>>(
        Xqh, Xql, Xkh, Xkl, Wqh, Wql, Wkh, Wkl, wq_b, wk_b, Qh, Ql, Kh, Kl);

    // K2: masked, pre-scaled scores (global_load_lds staging)
    scores_mfma<<<dim3(LL / 64, LL / 128, BB * HH), 256, 0, stream>>>(
        Qh, Ql, Kh, Kl, mask, S);

    // K3: entmax + head average (3-head ILP, 8 bisections + quad finish)
    entmax_sum<<<BB * LL, 256, 0, stream>>>(S, out);
}

// Round 10
// 229.503 us; speedup vs baseline: 1.1441x; 1.1441x over previous
//
#include <hip/hip_runtime.h>
#include <math.h>

#define BB 2
#define LL 1536
#define DD 768
#define HH 12
#define DKK 64
#define ZNEG -5.0e8f   // NEG/2: reference masks scores to -1e9, then z = scores/2

typedef __attribute__((ext_vector_type(8))) short bf16x8;           // 8 bf16 (4 VGPRs)
typedef __attribute__((ext_vector_type(8))) unsigned short u16x8;
typedef __attribute__((ext_vector_type(4))) float f32x4;

__device__ __forceinline__ unsigned short f32_to_bf16_rn(float x) {
    unsigned int u = __float_as_uint(x);
    u += 0x7fffu + ((u >> 16) & 1u);          // round-to-nearest-even
    return (unsigned short)(u >> 16);
}
__device__ __forceinline__ float bf16u_to_f32(unsigned short h) {
    return __uint_as_float(((unsigned int)h) << 16);
}

// Packed f32x2 -> bf16x2 (word0 = cvt(a), word1 = cvt(b)). No builtin on
// gfx950; inline asm per guide T12. Rounding mode of hi is IRRELEVANT for the
// split correctness: residual is computed against the stored hi exactly.
__device__ __forceinline__ unsigned int cvt_pk_bf16(float a, float b) {
    unsigned int r;
    asm("v_cvt_pk_bf16_f32 %0, %1, %2" : "=v"(r) : "v"(a), "v"(b));
    return r;
}

// Split 8 consecutive f32 into bf16 hi/lo halves; store 16 B of each.
// cvt_pk version: ~3 VALU/elem vs ~9 for the manual-RNE path.
__device__ __forceinline__ void split8(const float* __restrict__ gsrc,
                                       unsigned short* __restrict__ hdst,
                                       unsigned short* __restrict__ ldst) {
    float4 v0 = *reinterpret_cast<const float4*>(gsrc);
    float4 v1 = *reinterpret_cast<const float4*>(gsrc + 4);
    float f[8] = {v0.x, v0.y, v0.z, v0.w, v1.x, v1.y, v1.z, v1.w};
    unsigned int hw[4], lw[4];
    #pragma unroll
    for (int p = 0; p < 4; ++p) {
        const float a = f[2 * p], b = f[2 * p + 1];
        const unsigned int h = cvt_pk_bf16(a, b);
        const float ra = a - __uint_as_float(h << 16);          // exact residual vs stored hi
        const float rb = b - __uint_as_float(h & 0xffff0000u);
        hw[p] = h;
        lw[p] = cvt_pk_bf16(ra, rb);
    }
    *reinterpret_cast<uint4*>(hdst) = make_uint4(hw[0], hw[1], hw[2], hw[3]);
    *reinterpret_cast<uint4*>(ldst) = make_uint4(lw[0], lw[1], lw[2], lw[3]);
}

// ---------------------------------------------------------------------------
// Kernel 1: fused Q/K projection via split-bf16 MFMA (r7-bench structure,
// proven 231us total; only the split instructions changed to cvt_pk).
// out[m,n] = sum_k X[m,k]*W[n,k] + bias[n];  M=3072, N=768, K=768.
// Epilogue stores PRE-SPLIT bf16 hi/lo [B,L,D] row-major for K2's pure-copy
// staging.
// ---------------------------------------------------------------------------
__global__ __launch_bounds__(256) void proj_mfma(
    const float* __restrict__ Xq, const float* __restrict__ Xk,
    const float* __restrict__ Wq, const float* __restrict__ Wk,
    const float* __restrict__ bq, const float* __restrict__ bk,
    unsigned short* __restrict__ Qh, unsigned short* __restrict__ Ql,
    unsigned short* __restrict__ Kh, unsigned short* __restrict__ Kl)
{
    const float* X    = blockIdx.z ? Xk : Xq;
    const float* W    = blockIdx.z ? Wk : Wq;
    const float* bias = blockIdx.z ? bk : bq;
    unsigned short* Oh = blockIdx.z ? Kh : Qh;
    unsigned short* Ol = blockIdx.z ? Kl : Ql;

    __shared__ alignas(16) unsigned short Ah[8 * 64 * 8];  // 8 KB
    __shared__ alignas(16) unsigned short Al[8 * 64 * 8];  // 8 KB
    __shared__ alignas(16) unsigned short Bh[4 * 64 * 8];  // 4 KB
    __shared__ alignas(16) unsigned short Bl[4 * 64 * 8];  // 4 KB

    const int tid  = threadIdx.x;
    const int lane = tid & 63;
    const int w    = tid >> 6;
    const int wm   = w & 1;          // 2 m-halves of 64 rows
    const int wn   = w >> 1;         // 2 n-halves of 32 cols
    const int m0   = blockIdx.y * 128;
    const int n0   = blockIdx.x * 64;

    f32x4 acc[4][2] = {};

    for (int k0 = 0; k0 < DD; k0 += 32) {
        #pragma unroll
        for (int i = 0; i < 2; ++i) {
            const int c = tid + (i << 8);
            const int m = c >> 2, g = c & 3;
            const int slot = ((m >> 4) * 64 + (m & 15) + (g << 4)) * 8;
            split8(X + (size_t)(m0 + m) * DD + k0 + g * 8, Ah + slot, Al + slot);
        }
        {
            const int n = tid >> 2, g = tid & 3;
            const int slot = ((n >> 4) * 64 + (n & 15) + (g << 4)) * 8;
            split8(W + (size_t)(n0 + n) * DD + k0 + g * 8, Bh + slot, Bl + slot);
        }
        __syncthreads();

        bf16x8 aH[4], aL[4], bH[2], bL[2];
        #pragma unroll
        for (int fm = 0; fm < 4; ++fm) {
            const int f = wm * 4 + fm;
            aH[fm] = *reinterpret_cast<const bf16x8*>(Ah + (f * 64 + lane) * 8);
            aL[fm] = *reinterpret_cast<const bf16x8*>(Al + (f * 64 + lane) * 8);
        }
        #pragma unroll
        for (int fn = 0; fn < 2; ++fn) {
            const int f = wn * 2 + fn;
            bH[fn] = *reinterpret_cast<const bf16x8*>(Bh + (f * 64 + lane) * 8);
            bL[fn] = *reinterpret_cast<const bf16x8*>(Bl + (f * 64 + lane) * 8);
        }
        #pragma unroll
        for (int fm = 0; fm < 4; ++fm)
            #pragma unroll
            for (int fn = 0; fn < 2; ++fn) {
                acc[fm][fn] = __builtin_amdgcn_mfma_f32_16x16x32_bf16(aH[fm], bH[fn], acc[fm][fn], 0, 0, 0);
                acc[fm][fn] = __builtin_amdgcn_mfma_f32_16x16x32_bf16(aH[fm], bL[fn], acc[fm][fn], 0, 0, 0);
                acc[fm][fn] = __builtin_amdgcn_mfma_f32_16x16x32_bf16(aL[fm], bH[fn], acc[fm][fn], 0, 0, 0);
            }
        __syncthreads();
    }

    // ---- epilogue: C/D layout col=lane&15, row=(lane>>4)*4+reg [m89] ----
    const int r0 = (lane >> 4) << 2;
    const int cl = lane & 15;
    #pragma unroll
    for (int fn = 0; fn < 2; ++fn) {
        const int col = n0 + wn * 32 + fn * 16 + cl;
        const float bv = bias[col];
        #pragma unroll
        for (int fm = 0; fm < 4; ++fm) {
            const int row = m0 + wm * 64 + fm * 16 + r0;
            #pragma unroll
            for (int r = 0; r < 4; r += 2) {
                const float va = acc[fm][fn][r] + bv;
                const float vb = acc[fm][fn][r + 1] + bv;
                const unsigned int h = cvt_pk_bf16(va, vb);
                const float ra = va - __uint_as_float(h << 16);
                const float rb = vb - __uint_as_float(h & 0xffff0000u);
                const unsigned int lo = cvt_pk_bf16(ra, rb);
                const size_t oa = (size_t)(row + r) * DD + col;
                const size_t ob = (size_t)(row + r + 1) * DD + col;
                Oh[oa] = (unsigned short)(h & 0xffffu);
                Oh[ob] = (unsigned short)(h >> 16);
                Ol[oa] = (unsigned short)(lo & 0xffffu);
                Ol[ob] = (unsigned short)(lo >> 16);
            }
        }
    }
}

// ---------------------------------------------------------------------------
// Kernel 2: scores z = (q.k)/16, masked keys -> ZNEG, split-bf16 MFMA
// (r7-bench verified: coalesced PURE-COPY staging of pre-split hi/lo).
// Per (b,h): M=N=1536, K=64 (staged once). Tile 128x64, 4 waves x (64x32).
// ---------------------------------------------------------------------------
__global__ __launch_bounds__(256) void scores_mfma(
    const unsigned short* __restrict__ Qh, const unsigned short* __restrict__ Ql,
    const unsigned short* __restrict__ Kh, const unsigned short* __restrict__ Kl,
    const int* __restrict__ mask, float* __restrict__ S)
{
    const int bh = blockIdx.z;
    const int b  = bh / HH;
    const int h  = bh - b * HH;
    const int q0 = blockIdx.y * 128;
    const int n0 = blockIdx.x * 64;

    __shared__ alignas(16) unsigned short Ah[8 * 2 * 64 * 8];  // 16 KB
    __shared__ alignas(16) unsigned short Al[8 * 2 * 64 * 8];  // 16 KB
    __shared__ alignas(16) unsigned short Bh[4 * 2 * 64 * 8];  //  8 KB
    __shared__ alignas(16) unsigned short Bl[4 * 2 * 64 * 8];  //  8 KB

    const int tid  = threadIdx.x;
    const int lane = tid & 63;
    const int w    = tid >> 6;
    const int wm   = w & 1;
    const int wn   = w >> 1;

    // ---- stage A: 1024 16B chunks (m 0..127, c8 0..7), coalesced copy ----
    #pragma unroll
    for (int i = 0; i < 4; ++i) {
        const int c = tid + (i << 8);
        const int m = c >> 3, c8 = c & 7;
        const int qq = c8 >> 2, g = c8 & 3;
        const int slot = (((m >> 4) * 2 + qq) * 64 + (m & 15) + (g << 4)) * 8;
        const size_t o = (size_t)(b * LL + q0 + m) * DD + h * DKK + c8 * 8;
        *reinterpret_cast<u16x8*>(Ah + slot) = *reinterpret_cast<const u16x8*>(Qh + o);
        *reinterpret_cast<u16x8*>(Al + slot) = *reinterpret_cast<const u16x8*>(Ql + o);
    }
    // ---- stage B: 512 chunks (n 0..63, c8 0..7) ----
    #pragma unroll
    for (int i = 0; i < 2; ++i) {
        const int c = tid + (i << 8);
        const int n = c >> 3, c8 = c & 7;
        const int qq = c8 >> 2, g = c8 & 3;
        const int slot = (((n >> 4) * 2 + qq) * 64 + (n & 15) + (g << 4)) * 8;
        const size_t o = (size_t)(b * LL + n0 + n) * DD + h * DKK + c8 * 8;
        *reinterpret_cast<u16x8*>(Bh + slot) = *reinterpret_cast<const u16x8*>(Kh + o);
        *reinterpret_cast<u16x8*>(Bl + slot) = *reinterpret_cast<const u16x8*>(Kl + o);
    }
    __syncthreads();

    f32x4 acc[4][2] = {};
    #pragma unroll
    for (int qq = 0; qq < 2; ++qq) {
        bf16x8 aH[4], aL[4], bH[2], bL[2];
        #pragma unroll
        for (int fm = 0; fm < 4; ++fm) {
            const int f = (wm * 4 + fm) * 2 + qq;
            aH[fm] = *reinterpret_cast<const bf16x8*>(Ah + (f * 64 + lane) * 8);
            aL[fm] = *reinterpret_cast<const bf16x8*>(Al + (f * 64 + lane) * 8);
        }
        #pragma unroll
        for (int fn = 0; fn < 2; ++fn) {
            const int f = (wn * 2 + fn) * 2 + qq;
            bH[fn] = *reinterpret_cast<const bf16x8*>(Bh + (f * 64 + lane) * 8);
            bL[fn] = *reinterpret_cast<const bf16x8*>(Bl + (f * 64 + lane) * 8);
        }
        #pragma unroll
        for (int fm = 0; fm < 4; ++fm)
            #pragma unroll
            for (int fn = 0; fn < 2; ++fn) {
                acc[fm][fn] = __builtin_amdgcn_mfma_f32_16x16x32_bf16(aH[fm], bH[fn], acc[fm][fn], 0, 0, 0);
                acc[fm][fn] = __builtin_amdgcn_mfma_f32_16x16x32_bf16(aH[fm], bL[fn], acc[fm][fn], 0, 0, 0);
                acc[fm][fn] = __builtin_amdgcn_mfma_f32_16x16x32_bf16(aL[fm], bH[fn], acc[fm][fn], 0, 0, 0);
            }
    }

    // ---- epilogue: scale 1/16, mask, store f32 ----
    const int r0 = (lane >> 4) << 2;
    const int cl = lane & 15;
    #pragma unroll
    for (int fn = 0; fn < 2; ++fn) {
        const int col = n0 + wn * 32 + fn * 16 + cl;
        const int mk  = mask[b * LL + col];
        #pragma unroll
        for (int fm = 0; fm < 4; ++fm) {
            const int row = q0 + wm * 64 + fm * 16 + r0;
            const size_t base = ((size_t)bh * LL + row) * LL + col;
            #pragma unroll
            for (int r = 0; r < 4; ++r) {
                const float v = acc[fm][fn][r] * 0.0625f;   // (qk/8)/2
                S[base + (size_t)r * LL] = mk ? v : ZNEG;
            }
        }
    }
}

// ---------------------------------------------------------------------------
// Kernel 3: entmax-1.5 (r7-bench verified, 66us): wave-per-head, sequential
// 8 bisections + closed-form quadratic finish on A = {z > lo}.
// ---------------------------------------------------------------------------
__device__ __forceinline__ float waveReduceSum(float v) {
    #pragma unroll
    for (int off = 32; off > 0; off >>= 1) v += __shfl_xor(v, off, 64);
    return v;
}
__device__ __forceinline__ float waveReduceMax(float v) {
    #pragma unroll
    for (int off = 32; off > 0; off >>= 1) v = fmaxf(v, __shfl_xor(v, off, 64));
    return v;
}

__global__ __launch_bounds__(256) void entmax_sum(
    const float* __restrict__ S, float* __restrict__ out)
{
    const int bq = blockIdx.x;          // b*LL + q
    const int b  = bq / LL;
    const int q  = bq - b * LL;
    const int tid = threadIdx.x;
    const int w  = tid >> 6;            // wave 0..3
    const int l  = tid & 63;            // lane 0..63

    __shared__ float buf[4][LL];        // per-wave head-partials, 24 KB

    float acc[24];
    #pragma unroll
    for (int i = 0; i < 24; ++i) acc[i] = 0.0f;

    #pragma unroll
    for (int hh = 0; hh < 3; ++hh) {
        const int h = w + (hh << 2);
        const float* row = S + ((size_t)(b * HH + h) * LL + q) * LL + l * 24;

        float z[24];
        #pragma unroll
        for (int i = 0; i < 24; i += 4) {
            float4 v = *reinterpret_cast<const float4*>(row + i);
            z[i] = v.x; z[i + 1] = v.y; z[i + 2] = v.z; z[i + 3] = v.w;
        }

        // ---- wave max + shift ----
        float m = z[0];
        #pragma unroll
        for (int i = 1; i < 24; ++i) m = fmaxf(m, z[i]);
        m = waveReduceMax(m);
        #pragma unroll
        for (int i = 0; i < 24; ++i) z[i] -= m;

        // ---- 8 bisection steps: tau in [-1, 0], bracket -> 2^-8 ----
        float lo = -1.0f, hi_ = 0.0f;
        #pragma unroll
        for (int it = 0; it < 8; ++it) {
            const float tau = 0.5f * (lo + hi_);
            float s = 0.0f;
            #pragma unroll
            for (int i = 0; i < 24; ++i) {
                const float t = fmaxf(z[i] - tau, 0.0f);
                s = fmaf(t, t, s);
            }
            s = waveReduceSum(s);
            if (s >= 1.0f) lo = tau; else hi_ = tau;
        }

        // ---- closed-form quadratic finish on A = {z > lo} ----
        float s1 = 0.0f, s2 = 0.0f, cn = 0.0f;
        #pragma unroll
        for (int i = 0; i < 24; ++i) {
            const bool a = z[i] > lo;
            const float t = a ? z[i] : 0.0f;
            s1 += t;
            s2 = fmaf(t, t, s2);
            cn += a ? 1.0f : 0.0f;
        }
        s1 = waveReduceSum(s1);
        s2 = waveReduceSum(s2);
        cn = waveReduceSum(cn);
        const float disc = fmaxf(fmaf(s1, s1, -cn * (s2 - 1.0f)), 0.0f);
        const float tau = (s1 - sqrtf(disc)) / cn;   // cn >= 1 (max elem z=0 > lo)

        #pragma unroll
        for (int i = 0; i < 24; ++i) {
            const float t = fmaxf(z[i] - tau, 0.0f);
            acc[i] = fmaf(t, t, acc[i]);
        }
    }

    // ---- join the 4 waves' head-partials ----
    #pragma unroll
    for (int i = 0; i < 24; ++i) buf[w][l * 24 + i] = acc[i];
    __syncthreads();

    float* orow = out + (size_t)bq * LL;
    #pragma unroll
    for (int i = 0; i < 6; ++i) {
        const int c = tid + (i << 8);
        orow[c] = (buf[0][c] + buf[1][c] + buf[2][c] + buf[3][c]) * (1.0f / 12.0f);
    }
}

// ---------------------------------------------------------------------------
extern "C" void kernel_launch(void* const* d_in, const int* in_sizes, int n_in,
                              void* d_out, int out_size, void* d_ws, size_t ws_size,
                              hipStream_t stream) {
    (void)in_sizes; (void)n_in; (void)out_size; (void)ws_size;
    const float* query = (const float*)d_in[0];
    const float* key   = (const float*)d_in[1];
    const int*   mask  = (const int*)d_in[2];
    const float* wq_w  = (const float*)d_in[3];
    const float* wq_b  = (const float*)d_in[4];
    const float* wk_w  = (const float*)d_in[5];
    const float* wk_b  = (const float*)d_in[6];
    float* out = (float*)d_out;

    const size_t NE = (size_t)BB * LL * DD;         // 2359296 elems
    unsigned short* Qh = (unsigned short*)d_ws;     // 4.7 MB each
    unsigned short* Ql = Qh + NE;
    unsigned short* Kh = Ql + NE;
    unsigned short* Kl = Kh + NE;
    float* S = (float*)(Kl + NE);                   // [B,H,L,L] 226.5 MB

    // K1: projections -> pre-split bf16 hi/lo (z dim: 0 = Q, 1 = K)
    proj_mfma<<<dim3(DD / 64, (BB * LL) / 128, 2), 256, 0, stream>>>(
        query, key, wq_w, wk_w, wq_b, wk_b, Qh, Ql, Kh, Kl);

    // K2: masked, pre-scaled scores (coalesced copy staging, no conversion)
    scores_mfma<<<dim3(LL / 64, LL / 128, BB * HH), 256, 0, stream>>>(
        Qh, Ql, Kh, Kl, mask, S);

    // K3: entmax + head average (8 bisections + closed-form finish)
    entmax_sum<<<BB * LL, 256, 0, stream>>>(S, out);
}